// Round 2
// baseline (1085.731 us; speedup 1.0000x reference)
//
#include <hip/hip_runtime.h>
#include <stdint.h>

// LinearAttention: B=4 N=8192 C=1152 H=36 D=32
// Pipeline: convert->bf16, GEMM1(qkv,+ReLU), kv-reduce, attn-normalize, GEMM2(+bias)
// R5: GEMM schedule v4 — ds_reads pipelined ONE PHASE AHEAD of their MFMA quadrant,
//     1 barrier/phase (4/K-tile, was 8), single counted vmcnt(4) gate per K-tile.
//     R4's failure: reads+MFMA serialized (read->barrier->MFMA per phase) => K-tile
//     ~5980cyc = LDS 2300 + MFMA 2480 serial. v4 overlaps them (reads drain under
//     the previous quadrant's MFMAs).

#define HH 36
#define DD 32
#define CC 1152
#define NB 4
#define NN 8192
#define M_TOT (NB * NN)   // 32768
#define N1 (3 * HH * DD)  // 3456
#define HD (HH * DD)      // 1152
#define HPB 3
#define KVSPLIT 32

typedef __attribute__((ext_vector_type(8))) short bf16x8;
typedef __attribute__((ext_vector_type(4))) float f32x4;

__device__ __forceinline__ uint16_t f2b(float f) {
  union { float f; uint32_t u; } v; v.f = f;
  uint32_t u = v.u;
  return (uint16_t)((u + 0x7fffu + ((u >> 16) & 1u)) >> 16);
}
__device__ __forceinline__ float uasf(uint32_t u) {
  union { uint32_t u; float f; } v; v.u = u; return v.f;
}
__device__ __forceinline__ void unpack8v(uint4 u, f32x4& lo, f32x4& hi) {
  lo[0] = uasf(u.x << 16); lo[1] = uasf(u.x & 0xffff0000u);
  lo[2] = uasf(u.y << 16); lo[3] = uasf(u.y & 0xffff0000u);
  hi[0] = uasf(u.z << 16); hi[1] = uasf(u.z & 0xffff0000u);
  hi[2] = uasf(u.w << 16); hi[3] = uasf(u.w & 0xffff0000u);
}

// async global->LDS, 16B/lane; LDS dest is wave-uniform base (+lane*16 implicit)
#define GLOAD16(g, l)                                                        \
  __builtin_amdgcn_global_load_lds(                                          \
      (const __attribute__((address_space(1))) void*)(g),                    \
      (__attribute__((address_space(3))) void*)(l), 16, 0, 0)

// st_16x32 swizzle for a 128x64 bf16 half-tile (byte offset), XOR bit5 with bit9.
__device__ __forceinline__ int swz_off(int row, int col) {
  int off = ((row >> 4) * 2 + (col >> 5)) * 1024 + (row & 15) * 64 + (col & 31) * 2;
  return off ^ (((off >> 9) & 1) << 5);
}
// Inverse for staging (global_load_lds writes linearly; swizzle realized by
// permuting the per-lane GLOBAL source address — both-sides rule).
__device__ __forceinline__ void stage_decode(int d, int& row, int& col) {
  int lin = d ^ (((d >> 9) & 1) << 5);
  int s = lin >> 10;
  row = (s >> 1) * 16 + ((lin >> 6) & 15);
  col = (s & 1) * 32 + ((lin >> 1) & 31);
}

__global__ void zero_kernel(float* __restrict__ p, int n) {
  int i = blockIdx.x * blockDim.x + threadIdx.x;
  if (i < n) p[i] = 0.f;
}

__global__ void convert_kernel(const float* __restrict__ in, uint16_t* __restrict__ out, int n4) {
  int i = blockIdx.x * blockDim.x + threadIdx.x;
  if (i >= n4) return;
  float4 v = ((const float4*)in)[i];
  ushort4 o;
  o.x = f2b(v.x); o.y = f2b(v.y); o.z = f2b(v.z); o.w = f2b(v.w);
  ((ushort4*)out)[i] = o;
}

// in: [R][Cc] fp32 -> out: [Cc][R] bf16  (32x32 LDS tile transpose)
__global__ void transpose_convert_kernel(const float* __restrict__ in, uint16_t* __restrict__ out,
                                         int R, int Cc) {
  __shared__ uint16_t tile[32][33];
  int c0 = blockIdx.x * 32, r0 = blockIdx.y * 32;
  int tx = threadIdx.x & 31, ty = threadIdx.x >> 5;
#pragma unroll
  for (int i = 0; i < 4; i++) {
    int r = ty + i * 8;
    tile[r][tx] = f2b(in[(size_t)(r0 + r) * Cc + c0 + tx]);
  }
  __syncthreads();
#pragma unroll
  for (int i = 0; i < 4; i++) {
    int c = ty + i * 8;
    out[(size_t)(c0 + c) * R + r0 + tx] = tile[tx][c];
  }
}

// ============================ 256x256 pipelined GEMM ===========================
// C[m][n] = sum_k A[m][k] * BT[n][k], K=1152 (18 K-tiles of 64).
// 512 threads = 8 waves (2M x 4N); per-wave 128x64 (acc[8][4] f32x4).
// LDS: lds[buf][slot][8192], slots {0:A rows0-127, 1:A rows128-255, 2:B0, 3:B1}.
// v4 schedule per K-tile T (cur=T&1), reads issued ONE phase before use:
//   P1: read bH(T)      |             | Q1 = aL x bL | lgkm0 | bar
//   P2: read aH(T)      | STAGE B(T+2)| Q2 = aL x bH | lgkm0 vmcnt(4) | bar
//   P3: read aL(T+1)    | STAGE A(T+2)| Q3 = aH x bH | bar
//   P4:                 |             | Q4 = aH x bL | read bL(T+1) | bar
// Gate math (per-thread loads, 4 B + 4 A per K-tile): at P2(T) gate the un-landed
// worst set is {B(T+1),A(T+1),B(T+2)}=12 -> vmcnt(4) guarantees A(T+1),B(T+1),
// allows the just-issued B(T+2). Stages 2 tiles ahead target the CURRENT buffer
// (cur(T+2)==cur); WAR-safe because lgkm0 at P1/P2 end forces all waves' reads of
// those slots drained before the staging phase begins.
template <int EPI, int NREAL>
__global__ __launch_bounds__(512, 2)
void gemm256_kernel(const uint16_t* __restrict__ A, const uint16_t* __restrict__ BT,
                    uint16_t* __restrict__ outb, float* __restrict__ outf,
                    const float* __restrict__ bias) {
  constexpr int K = 1152;
  constexpr int NTT = K / 64;               // 18
  constexpr int NTx = (EPI == 0) ? 14 : 5;  // N-tiles (padded N: 3584 / 1280)
  __shared__ uint16_t lds[2][4][8192];      // 128 KiB -> 1 block/CU, 2 waves/SIMD

  const int flat = blockIdx.y * NTx + blockIdx.x;  // nwg = 1792 / 640, both %8==0
  const int xcd = flat & 7, sg = flat >> 3;
  const int n0 = (sg % NTx) * 256;
  const int m0 = ((sg / NTx) * 8 + xcd) * 256;  // xcd owns m within band of 8
  const int tid = threadIdx.x;
  const int lane = tid & 63, w = tid >> 6;
  const int wm = w >> 2, wn = w & 3;
  const int l15 = lane & 15, q4 = lane >> 4;

  int r0, c0, r1, c1;
  stage_decode(tid * 16, r0, c0);
  stage_decode(tid * 16 + 8192, r1, c1);
  const size_t go0 = (size_t)r0 * K + c0;
  const size_t go1 = (size_t)r1 * K + c1;
  const uint16_t* A0p = A + (size_t)m0 * K;
  const uint16_t* A1p = A + (size_t)(m0 + 128) * K;
  const uint16_t* B0p = BT + (size_t)n0 * K;
  const uint16_t* B1p = BT + (size_t)(n0 + 128) * K;
  const int stl = w * 512;  // wave-uniform LDS element base for issue 0

#define STAGE(bp, kt, slot)                                                  \
  {                                                                          \
    const uint16_t* _g = (bp) + (size_t)(kt) * 64;                           \
    GLOAD16(_g + go0, (slot) + stl);                                         \
    GLOAD16(_g + go1, (slot) + 4096 + stl);                                  \
  }
#define RD(ptr, row, col) \
  (*(const bf16x8*)((const char*)(ptr) + swz_off((row), (col))))
#define BAR() asm volatile("s_barrier" ::: "memory")
#define LGKM0() asm volatile("s_waitcnt lgkmcnt(0)" ::: "memory")

  f32x4 acc[8][4] = {};
  bf16x8 aL[4][2], aH[4][2], bl[2][2], bh[2][2];
  const int bro = (wn & 1) * 64;

  // prologue: stage tile0 fully, then tile1 B, then tile1 A (16 loads/thread)
  STAGE(A0p, 0, &lds[0][0][0]);
  STAGE(A1p, 0, &lds[0][1][0]);
  STAGE(B0p, 0, &lds[0][2][0]);
  STAGE(B1p, 0, &lds[0][3][0]);
  STAGE(B0p, 1, &lds[1][2][0]);
  STAGE(B1p, 1, &lds[1][3][0]);
  STAGE(A0p, 1, &lds[1][0][0]);
  STAGE(A1p, 1, &lds[1][1][0]);
  asm volatile("s_waitcnt vmcnt(8)" ::: "memory");  // tile0's 8 loads landed
  BAR();
  {
    const uint16_t* sA0 = &lds[0][wm][0];
    const uint16_t* sB0 = &lds[0][2 + (wn >> 1)][0];
#pragma unroll
    for (int i = 0; i < 4; i++)
#pragma unroll
      for (int kk = 0; kk < 2; kk++)
        aL[i][kk] = RD(sA0, i * 16 + l15, kk * 32 + q4 * 8);
#pragma unroll
    for (int j = 0; j < 2; j++)
#pragma unroll
      for (int kk = 0; kk < 2; kk++)
        bl[j][kk] = RD(sB0, bro + j * 16 + l15, kk * 32 + q4 * 8);
  }

#pragma unroll 1
  for (int T = 0; T < NTT; T++) {
    const int cur = T & 1;
    const int t2 = (T + 2 < NTT) ? T + 2 : NTT - 1;  // clamped restage: identical
    const uint16_t* sA = &lds[cur][wm][0];           // data, benign overwrite
    const uint16_t* sB = &lds[cur][2 + (wn >> 1)][0];
    const uint16_t* sAn = &lds[cur ^ 1][wm][0];
    const uint16_t* sBn = &lds[cur ^ 1][2 + (wn >> 1)][0];
    // ---- P1: issue bH(T); Q1 = aL x bL ----
#pragma unroll
    for (int j = 0; j < 2; j++)
#pragma unroll
      for (int kk = 0; kk < 2; kk++)
        bh[j][kk] = RD(sB, bro + 32 + j * 16 + l15, kk * 32 + q4 * 8);
    __builtin_amdgcn_s_setprio(1);
#pragma unroll
    for (int i = 0; i < 4; i++)
#pragma unroll
      for (int j = 0; j < 2; j++)
#pragma unroll
        for (int kk = 0; kk < 2; kk++)
          acc[i][j] = __builtin_amdgcn_mfma_f32_16x16x32_bf16(
              aL[i][kk], bl[j][kk], acc[i][j], 0, 0, 0);
    __builtin_amdgcn_s_setprio(0);
    LGKM0();  // bh drained: next phase stages into B slots' buffer peer-safely
    BAR();
    // ---- P2: issue aH(T); stage B(T+2) -> lds[cur][2,3]; Q2 = aL x bH ----
#pragma unroll
    for (int i = 0; i < 4; i++)
#pragma unroll
      for (int kk = 0; kk < 2; kk++)
        aH[i][kk] = RD(sA, 64 + i * 16 + l15, kk * 32 + q4 * 8);
    STAGE(B0p, t2, &lds[cur][2][0]);
    STAGE(B1p, t2, &lds[cur][3][0]);
    __builtin_amdgcn_s_setprio(1);
#pragma unroll
    for (int i = 0; i < 4; i++)
#pragma unroll
      for (int j = 0; j < 2; j++)
#pragma unroll
        for (int kk = 0; kk < 2; kk++)
          acc[i][2 + j] = __builtin_amdgcn_mfma_f32_16x16x32_bf16(
              aL[i][kk], bh[j][kk], acc[i][2 + j], 0, 0, 0);
    __builtin_amdgcn_s_setprio(0);
    LGKM0();                                          // aH drained before A-stage
    asm volatile("s_waitcnt vmcnt(4)" ::: "memory");  // A(T+1),B(T+1) resident
    BAR();
    // ---- P3: issue aL(T+1) from next buf; stage A(T+2); Q3 = aH x bH ----
#pragma unroll
    for (int i = 0; i < 4; i++)
#pragma unroll
      for (int kk = 0; kk < 2; kk++)
        aL[i][kk] = RD(sAn, i * 16 + l15, kk * 32 + q4 * 8);
    STAGE(A0p, t2, &lds[cur][0][0]);
    STAGE(A1p, t2, &lds[cur][1][0]);
    __builtin_amdgcn_s_setprio(1);
#pragma unroll
    for (int i = 0; i < 4; i++)
#pragma unroll
      for (int j = 0; j < 2; j++)
#pragma unroll
        for (int kk = 0; kk < 2; kk++)
          acc[4 + i][2 + j] = __builtin_amdgcn_mfma_f32_16x16x32_bf16(
              aH[i][kk], bh[j][kk], acc[4 + i][2 + j], 0, 0, 0);
    __builtin_amdgcn_s_setprio(0);
    BAR();
    // ---- P4: Q4 = aH x bL; then issue bL(T+1) (same regs, WAR after MFMA) ----
    __builtin_amdgcn_s_setprio(1);
#pragma unroll
    for (int i = 0; i < 4; i++)
#pragma unroll
      for (int j = 0; j < 2; j++)
#pragma unroll
        for (int kk = 0; kk < 2; kk++)
          acc[4 + i][j] = __builtin_amdgcn_mfma_f32_16x16x32_bf16(
              aH[i][kk], bl[j][kk], acc[4 + i][j], 0, 0, 0);
    __builtin_amdgcn_s_setprio(0);
#pragma unroll
    for (int j = 0; j < 2; j++)
#pragma unroll
      for (int kk = 0; kk < 2; kk++)
        bl[j][kk] = RD(sBn, bro + j * 16 + l15, kk * 32 + q4 * 8);
    BAR();
  }
  asm volatile("s_waitcnt vmcnt(0)" ::: "memory");  // drain tail DMAs pre-endpgm
  // epilogue
#pragma unroll
  for (int mi = 0; mi < 8; mi++) {
    const int row = m0 + wm * 128 + mi * 16 + q4 * 4;
#pragma unroll
    for (int nj = 0; nj < 4; nj++) {
      const int col = n0 + wn * 64 + nj * 16 + l15;
      if (col < NREAL) {
#pragma unroll
        for (int r = 0; r < 4; r++) {
          float v = acc[mi][nj][r];
          if (EPI == 0) {
            if (col < 2 * HD) v = fmaxf(v, 0.f);
            outb[(size_t)(row + r) * NREAL + col] = f2b(v);
          } else {
            outf[(size_t)(row + r) * NREAL + col] = v + bias[col];
          }
        }
      }
    }
  }
#undef STAGE
#undef RD
#undef BAR
#undef LGKM0
}

// kv[d][e] = sum_n k[n,d]*v[n,e] per (b,h); stored transposed kvT[bh][e*32+d]. Also ksum[bh][d].
__global__ __launch_bounds__(64)
void kv_kernel(const uint16_t* __restrict__ qkvb, float* __restrict__ kvT, float* __restrict__ ksum) {
  __shared__ float kb[32][40];
  __shared__ float vb[32][40];
  const int bh = blockIdx.x / KVSPLIT;
  const int sp = blockIdx.x % KVSPLIT;
  const int b = bh / HH, h = bh % HH;
  const int t = threadIdx.x;
  const int d0 = (t >> 3) * 4, e0 = (t & 7) * 4;
  const int m0 = b * NN + sp * (NN / KVSPLIT);
  const size_t koff = (size_t)HD + h * DD;
  const size_t voff = (size_t)2 * HD + h * DD;
  float acc[4][4] = {};
  float ks[4] = {};
  const int srow = t >> 1, sseg = (t & 1) * 16;
  for (int c = 0; c < NN / KVSPLIT; c += 32) {
    const uint16_t* kp = qkvb + (size_t)(m0 + c + srow) * N1 + koff + sseg;
    const uint16_t* vp = qkvb + (size_t)(m0 + c + srow) * N1 + voff + sseg;
    uint4 kr0 = *(const uint4*)kp;
    uint4 kr1 = *(const uint4*)(kp + 8);
    uint4 vr0 = *(const uint4*)vp;
    uint4 vr1 = *(const uint4*)(vp + 8);
    f32x4 klo, khi, klo2, khi2, vlo, vhi, vlo2, vhi2;
    unpack8v(kr0, klo, khi); unpack8v(kr1, klo2, khi2);
    unpack8v(vr0, vlo, vhi); unpack8v(vr1, vlo2, vhi2);
    __syncthreads();
    *(f32x4*)&kb[srow][sseg + 0] = klo;  *(f32x4*)&kb[srow][sseg + 4] = khi;
    *(f32x4*)&kb[srow][sseg + 8] = klo2; *(f32x4*)&kb[srow][sseg + 12] = khi2;
    *(f32x4*)&vb[srow][sseg + 0] = vlo;  *(f32x4*)&vb[srow][sseg + 4] = vhi;
    *(f32x4*)&vb[srow][sseg + 8] = vlo2; *(f32x4*)&vb[srow][sseg + 12] = vhi2;
    __syncthreads();
#pragma unroll 8
    for (int n = 0; n < 32; n++) {
      f32x4 kd = *(const f32x4*)&kb[n][d0];
      f32x4 ve = *(const f32x4*)&vb[n][e0];
#pragma unroll
      for (int i = 0; i < 4; i++)
#pragma unroll
        for (int j = 0; j < 4; j++) acc[i][j] += kd[i] * ve[j];
      if ((t & 7) == 0) {
#pragma unroll
        for (int i = 0; i < 4; i++) ks[i] += kd[i];
      }
    }
  }
#pragma unroll
  for (int i = 0; i < 4; i++)
#pragma unroll
    for (int j = 0; j < 4; j++)
      atomicAdd(&kvT[(size_t)bh * 1024 + (e0 + j) * DD + d0 + i], acc[i][j]);
  if ((t & 7) == 0) {
#pragma unroll
    for (int i = 0; i < 4; i++) atomicAdd(&ksum[bh * DD + d0 + i], ks[i]);
  }
}

// attn[m][h*32+e] = (sum_d q*kv[d][e]) / (sum_d q*ksum[d] + 1e-6), bf16 out.
__global__ __launch_bounds__(256)
void attn_kernel(const uint16_t* __restrict__ qkvb, const float* __restrict__ kvT,
                 const float* __restrict__ ksum, uint16_t* __restrict__ attn) {
  const int t = threadIdx.x;
  const int lane = t & 63, w = t >> 6;
  const int mbase = blockIdx.x * 256 + w * 64;
  const int b = mbase >> 13;
  const int e = lane & 31, dh = lane >> 5;
  const int h0 = blockIdx.y * HPB;
  for (int hh = 0; hh < HPB; hh++) {
    const int h = h0 + hh;
    const int bh = b * HH + h;
    const float* kvp = kvT + (size_t)bh * 1024 + e * DD + dh * 16;
    f32x4 kva = *(const f32x4*)(kvp + 0);
    f32x4 kvb2 = *(const f32x4*)(kvp + 4);
    f32x4 kvc = *(const f32x4*)(kvp + 8);
    f32x4 kvd = *(const f32x4*)(kvp + 12);
    const float* ksp = ksum + bh * DD + dh * 16;
    f32x4 ksa = *(const f32x4*)(ksp + 0);
    f32x4 ksb = *(const f32x4*)(ksp + 4);
    f32x4 ksc = *(const f32x4*)(ksp + 8);
    f32x4 ksd = *(const f32x4*)(ksp + 12);
#pragma unroll 4
    for (int r = 0; r < 64; r++) {
      const int m = mbase + r;
      const uint16_t* qp = qkvb + (size_t)m * N1 + h * DD + dh * 16;
      uint4 q0 = *(const uint4*)qp;
      uint4 q1 = *(const uint4*)(qp + 8);
      f32x4 qa, qb2, qc, qd;
      unpack8v(q0, qa, qb2);
      unpack8v(q1, qc, qd);
      float o = 0.f, den = 0.f;
#pragma unroll
      for (int ii = 0; ii < 4; ii++) {
        o += qa[ii] * kva[ii];  den += qa[ii] * ksa[ii];
        o += qb2[ii] * kvb2[ii]; den += qb2[ii] * ksb[ii];
        o += qc[ii] * kvc[ii];  den += qc[ii] * ksc[ii];
        o += qd[ii] * kvd[ii];  den += qd[ii] * ksd[ii];
      }
      o += __shfl_xor(o, 32);
      den += __shfl_xor(den, 32);
      float res = o / (den + 1e-6f);
      if (dh == 0) attn[(size_t)m * HD + h * DD + e] = f2b(res);
    }
  }
}

extern "C" void kernel_launch(void* const* d_in, const int* in_sizes, int n_in,
                              void* d_out, int out_size, void* d_ws, size_t ws_size,
                              hipStream_t stream) {
  const float* x = (const float*)d_in[0];
  const float* Wqkv = (const float*)d_in[1];
  const float* Wout = (const float*)d_in[2];
  const float* bout = (const float*)d_in[3];
  float* y = (float*)d_out;
  char* ws = (char*)d_ws;
  // workspace layout (bytes):
  //   xb/attn   @ 0          75,497,472  (32768x1152 bf16)
  //   wqkvT     @ 75497472    8,257,536  (3584x1152 bf16, rows>=3456 garbage pad)
  //   qkvb      @ 83755008  226,492,416  (32768x3456 bf16)
  //   kvT       @ 310247424     589,824
  //   ksum      @ 310837248      18,432   total 310,855,680
  //   woutT aliases qkvb (1280x1152 bf16, rows>=1152 garbage; qkvb dead after attn)
  uint16_t* xb = (uint16_t*)ws;
  uint16_t* wqkvT = (uint16_t*)(ws + 75497472);
  uint16_t* qkvb = (uint16_t*)(ws + 83755008);
  float* kvT = (float*)(ws + 310247424);
  float* ksum = (float*)(ws + 310837248);
  uint16_t* woutT = qkvb;
  uint16_t* attn = xb;  // alias: xb dead after GEMM1

  zero_kernel<<<(152064 + 255) / 256, 256, 0, stream>>>(kvT, 152064);  // kvT+ksum contiguous
  convert_kernel<<<(M_TOT * CC / 4) / 256, 256, 0, stream>>>(x, xb, M_TOT * CC / 4);
  transpose_convert_kernel<<<dim3(N1 / 32, CC / 32), 256, 0, stream>>>(Wqkv, wqkvT, CC, N1);
  gemm256_kernel<0, N1><<<dim3(14, 128), 512, 0, stream>>>(xb, wqkvT, qkvb, nullptr, nullptr);
  kv_kernel<<<144 * KVSPLIT, 64, 0, stream>>>(qkvb, kvT, ksum);
  attn_kernel<<<dim3(M_TOT / 256, HH / HPB), 256, 0, stream>>>(qkvb, kvT, ksum, attn);
  transpose_convert_kernel<<<dim3(CC / 32, CC / 32), 256, 0, stream>>>(Wout, woutT, CC, CC);
  gemm256_kernel<1, HD><<<dim3(5, 128), 512, 0, stream>>>(attn, woutT, nullptr, y, bout);
}

// Round 3
// 948.478 us; speedup vs baseline: 1.1447x; 1.1447x over previous
//
#include <hip/hip_runtime.h>
#include <stdint.h>

// LinearAttention: B=4 N=8192 C=1152 H=36 D=32
// Pipeline: convert->bf16, GEMM1(qkv,+ReLU), kv-reduce, attn-normalize, GEMM2(+bias)
// R6: GEMM1 = R4's 256x256 8-phase schedule (verified == m201 template) with the
//     two deviations fixed: (1) REMOVED sched_barrier(0) after lgkm0 (m141: that
//     pin alone costs ~40%; rule #18 applies only to inline-asm ds_reads, ours are
//     compiler-visible), (2) ADDED lgkmcnt(8) partial-drain hint at the 12-read
//     phase. GEMM2 = reverted to the proven R3 128x128 kernel (4 blocks/CU,
//     cross-block overlap; better tail at small N).

#define HH 36
#define DD 32
#define CC 1152
#define NB 4
#define NN 8192
#define M_TOT (NB * NN)   // 32768
#define N1 (3 * HH * DD)  // 3456
#define HD (HH * DD)      // 1152
#define HPB 3
#define KVSPLIT 32

typedef __attribute__((ext_vector_type(8))) short bf16x8;
typedef __attribute__((ext_vector_type(4))) float f32x4;

__device__ __forceinline__ uint16_t f2b(float f) {
  union { float f; uint32_t u; } v; v.f = f;
  uint32_t u = v.u;
  return (uint16_t)((u + 0x7fffu + ((u >> 16) & 1u)) >> 16);
}
__device__ __forceinline__ float uasf(uint32_t u) {
  union { uint32_t u; float f; } v; v.u = u; return v.f;
}
__device__ __forceinline__ void unpack8v(uint4 u, f32x4& lo, f32x4& hi) {
  lo[0] = uasf(u.x << 16); lo[1] = uasf(u.x & 0xffff0000u);
  lo[2] = uasf(u.y << 16); lo[3] = uasf(u.y & 0xffff0000u);
  hi[0] = uasf(u.z << 16); hi[1] = uasf(u.z & 0xffff0000u);
  hi[2] = uasf(u.w << 16); hi[3] = uasf(u.w & 0xffff0000u);
}

// async global->LDS, 16B/lane; LDS dest is wave-uniform base (+lane*16 implicit)
#define GLOAD16(g, l)                                                        \
  __builtin_amdgcn_global_load_lds(                                          \
      (const __attribute__((address_space(1))) void*)(g),                    \
      (__attribute__((address_space(3))) void*)(l), 16, 0, 0)

// st_16x32 swizzle for a 128x64 bf16 half-tile (byte offset), XOR bit5 with bit9.
__device__ __forceinline__ int swz_off(int row, int col) {
  int off = ((row >> 4) * 2 + (col >> 5)) * 1024 + (row & 15) * 64 + (col & 31) * 2;
  return off ^ (((off >> 9) & 1) << 5);
}
// Inverse for staging (global_load_lds writes linearly; swizzle realized by
// permuting the per-lane GLOBAL source address — both-sides rule).
__device__ __forceinline__ void stage_decode(int d, int& row, int& col) {
  int lin = d ^ (((d >> 9) & 1) << 5);
  int s = lin >> 10;
  row = (s >> 1) * 16 + ((lin >> 6) & 15);
  col = (s & 1) * 32 + ((lin >> 1) & 31);
}

__global__ void zero_kernel(float* __restrict__ p, int n) {
  int i = blockIdx.x * blockDim.x + threadIdx.x;
  if (i < n) p[i] = 0.f;
}

__global__ void convert_kernel(const float* __restrict__ in, uint16_t* __restrict__ out, int n4) {
  int i = blockIdx.x * blockDim.x + threadIdx.x;
  if (i >= n4) return;
  float4 v = ((const float4*)in)[i];
  ushort4 o;
  o.x = f2b(v.x); o.y = f2b(v.y); o.z = f2b(v.z); o.w = f2b(v.w);
  ((ushort4*)out)[i] = o;
}

// in: [R][Cc] fp32 -> out: [Cc][R] bf16  (32x32 LDS tile transpose)
__global__ void transpose_convert_kernel(const float* __restrict__ in, uint16_t* __restrict__ out,
                                         int R, int Cc) {
  __shared__ uint16_t tile[32][33];
  int c0 = blockIdx.x * 32, r0 = blockIdx.y * 32;
  int tx = threadIdx.x & 31, ty = threadIdx.x >> 5;
#pragma unroll
  for (int i = 0; i < 4; i++) {
    int r = ty + i * 8;
    tile[r][tx] = f2b(in[(size_t)(r0 + r) * Cc + c0 + tx]);
  }
  __syncthreads();
#pragma unroll
  for (int i = 0; i < 4; i++) {
    int c = ty + i * 8;
    out[(size_t)(c0 + c) * R + r0 + tx] = tile[tx][c];
  }
}

// ===================== 256x256 8-phase GEMM (m201 template) ====================
// C[m][n] = sum_k A[m][k] * BT[n][k], K=1152 (18 K-tiles of 64).
// 512 threads = 8 waves (2M x 4N); per-wave 128x64 (acc[8][4] f32x4).
// LDS: lds[buf][slot][8192], slots {0:A rows0-127, 1:A rows128-255, 2:B0, 3:B1}.
// Per K-tile T (cur=T&1), 4 phases, each {reads; stage 1 half-tile; bar; lgkm0;
// prio1; 16 MFMA; prio0; bar}:
//   ph1: read aL(8)+bL(4) [lgkmcnt(8) hint] | stage A0(T+1)->[cur^1][0] | Q_LL
//   ph2: read bH(4)                         | stage B0(T+1)->[cur^1][2] | Q_LH
//   ph3: read aH(8)                         | stage B1(T+2)->[cur][3]   | Q_HH
//   ph4: (no reads)                         | stage A1(T+2)->[cur][1]   | Q_HL
//        then vmcnt(4) gate; bar.
// Gate: vmcnt(4) leaves the newest 2 half-tiles (ph3,ph4 stages) in flight and
// guarantees everything <= ph2(T): A0(T+1)@ph1(T), B0(T+1)@ph2(T), B1(T+1)@
// ph3(T-1), A1(T+1)@ph4(T-1) => all of T+1 resident. Slot WAR: A slots die after
// ph3, B slots after ph2; every stage lands >=1 phase after its slot's last read
// (barrier windows make that safe). Never vmcnt(0) in the loop.
template <int EPI, int NREAL>
__global__ __launch_bounds__(512, 2)
void gemm256_kernel(const uint16_t* __restrict__ A, const uint16_t* __restrict__ BT,
                    uint16_t* __restrict__ outb, float* __restrict__ outf,
                    const float* __restrict__ bias) {
  constexpr int K = 1152;
  constexpr int NTT = K / 64;               // 18
  constexpr int NTx = (EPI == 0) ? 14 : 5;  // N-tiles (padded N)
  __shared__ uint16_t lds[2][4][8192];      // 128 KiB -> 1 block/CU, 2 waves/SIMD

  const int flat = blockIdx.y * NTx + blockIdx.x;  // nwg % 8 == 0
  const int xcd = flat & 7, sg = flat >> 3;
  const int n0 = (sg % NTx) * 256;
  const int m0 = ((sg / NTx) * 8 + xcd) * 256;  // xcd owns m within band of 8
  const int tid = threadIdx.x;
  const int lane = tid & 63, w = tid >> 6;
  const int wm = w >> 2, wn = w & 3;
  const int l15 = lane & 15, q4 = lane >> 4;

  int r0, c0, r1, c1;
  stage_decode(tid * 16, r0, c0);
  stage_decode(tid * 16 + 8192, r1, c1);
  const size_t go0 = (size_t)r0 * K + c0;
  const size_t go1 = (size_t)r1 * K + c1;
  const uint16_t* A0p = A + (size_t)m0 * K;
  const uint16_t* A1p = A + (size_t)(m0 + 128) * K;
  const uint16_t* B0p = BT + (size_t)n0 * K;
  const uint16_t* B1p = BT + (size_t)(n0 + 128) * K;
  const int stl = w * 512;  // wave-uniform LDS element base, issue 0

#define STAGE(bp, kt, slot)                                                  \
  {                                                                          \
    const uint16_t* _g = (bp) + (size_t)(kt) * 64;                           \
    GLOAD16(_g + go0, (slot) + stl);                                         \
    GLOAD16(_g + go1, (slot) + 4096 + stl);                                  \
  }
#define RD(ptr, row, col) \
  (*(const bf16x8*)((const char*)(ptr) + swz_off((row), (col))))
#define LGKM0() asm volatile("s_waitcnt lgkmcnt(0)" ::: "memory")

  f32x4 acc[8][4] = {};
  bf16x8 a[4][2], b[2][2][2];  // a: current A-half; b[0]=bL, b[1]=bH

  // prologue: 12 issues/thread; vmcnt(4) -> tile0's 8 landed, tile1's B1/A1 fly
  STAGE(B1p, 0, &lds[0][3][0]);
  STAGE(A1p, 0, &lds[0][1][0]);
  STAGE(A0p, 0, &lds[0][0][0]);
  STAGE(B0p, 0, &lds[0][2][0]);
  STAGE(B1p, 1, &lds[1][3][0]);
  STAGE(A1p, 1, &lds[1][1][0]);
  asm volatile("s_waitcnt vmcnt(4)" ::: "memory");
  __builtin_amdgcn_s_barrier();

#pragma unroll 2
  for (int T = 0; T < NTT; T++) {
    const int cur = T & 1;
    const int tn = (T + 1 < NTT) ? T + 1 : NTT - 1;   // clamped restage:
    const int tn2 = (T + 2 < NTT) ? T + 2 : NTT - 1;  // identical data, benign
    const uint16_t* sA = &lds[cur][wm][0];
    const uint16_t* sB = &lds[cur][2 + (wn >> 1)][0];
    const int bro = (wn & 1) * 64;
    // ---- phase 1: read aL + bL; stage A0(T+1); Q_LL ----
#pragma unroll
    for (int i = 0; i < 4; i++)
#pragma unroll
      for (int kk = 0; kk < 2; kk++)
        a[i][kk] = RD(sA, i * 16 + l15, kk * 32 + q4 * 8);
#pragma unroll
    for (int j = 0; j < 2; j++)
#pragma unroll
      for (int kk = 0; kk < 2; kk++)
        b[0][j][kk] = RD(sB, bro + j * 16 + l15, kk * 32 + q4 * 8);
    STAGE(A0p, tn, &lds[cur ^ 1][0][0]);
    asm volatile("s_waitcnt lgkmcnt(8)" ::: "memory");  // partial drain hint
    __builtin_amdgcn_s_barrier();
    LGKM0();
    __builtin_amdgcn_s_setprio(1);
#pragma unroll
    for (int i = 0; i < 4; i++)
#pragma unroll
      for (int j = 0; j < 2; j++)
#pragma unroll
        for (int kk = 0; kk < 2; kk++)
          acc[i][j] = __builtin_amdgcn_mfma_f32_16x16x32_bf16(
              a[i][kk], b[0][j][kk], acc[i][j], 0, 0, 0);
    __builtin_amdgcn_s_setprio(0);
    __builtin_amdgcn_s_barrier();
    // ---- phase 2: read bH; stage B0(T+1); Q_LH ----
#pragma unroll
    for (int j = 0; j < 2; j++)
#pragma unroll
      for (int kk = 0; kk < 2; kk++)
        b[1][j][kk] = RD(sB, bro + 32 + j * 16 + l15, kk * 32 + q4 * 8);
    STAGE(B0p, tn, &lds[cur ^ 1][2][0]);
    __builtin_amdgcn_s_barrier();
    LGKM0();
    __builtin_amdgcn_s_setprio(1);
#pragma unroll
    for (int i = 0; i < 4; i++)
#pragma unroll
      for (int j = 0; j < 2; j++)
#pragma unroll
        for (int kk = 0; kk < 2; kk++)
          acc[i][2 + j] = __builtin_amdgcn_mfma_f32_16x16x32_bf16(
              a[i][kk], b[1][j][kk], acc[i][2 + j], 0, 0, 0);
    __builtin_amdgcn_s_setprio(0);
    __builtin_amdgcn_s_barrier();
    // ---- phase 3: read aH; stage B1(T+2) into live buf (B dead after ph2); Q_HH ----
#pragma unroll
    for (int i = 0; i < 4; i++)
#pragma unroll
      for (int kk = 0; kk < 2; kk++)
        a[i][kk] = RD(sA, 64 + i * 16 + l15, kk * 32 + q4 * 8);
    STAGE(B1p, tn2, &lds[cur][3][0]);
    __builtin_amdgcn_s_barrier();
    LGKM0();
    __builtin_amdgcn_s_setprio(1);
#pragma unroll
    for (int i = 0; i < 4; i++)
#pragma unroll
      for (int j = 0; j < 2; j++)
#pragma unroll
        for (int kk = 0; kk < 2; kk++)
          acc[4 + i][2 + j] = __builtin_amdgcn_mfma_f32_16x16x32_bf16(
              a[i][kk], b[1][j][kk], acc[4 + i][2 + j], 0, 0, 0);
    __builtin_amdgcn_s_setprio(0);
    __builtin_amdgcn_s_barrier();
    // ---- phase 4: stage A1(T+2) into live buf (A dead after ph3); Q_HL; gate ----
    STAGE(A1p, tn2, &lds[cur][1][0]);
    __builtin_amdgcn_s_barrier();
    __builtin_amdgcn_s_setprio(1);
#pragma unroll
    for (int i = 0; i < 4; i++)
#pragma unroll
      for (int j = 0; j < 2; j++)
#pragma unroll
        for (int kk = 0; kk < 2; kk++)
          acc[4 + i][j] = __builtin_amdgcn_mfma_f32_16x16x32_bf16(
              a[i][kk], b[0][j][kk], acc[4 + i][j], 0, 0, 0);
    __builtin_amdgcn_s_setprio(0);
    asm volatile("s_waitcnt vmcnt(4)" ::: "memory");  // all of T+1 resident
    __builtin_amdgcn_s_barrier();
  }
  asm volatile("s_waitcnt vmcnt(0)" ::: "memory");  // drain tail DMAs pre-endpgm
  // epilogue
#pragma unroll
  for (int mi = 0; mi < 8; mi++) {
    const int row = m0 + wm * 128 + mi * 16 + q4 * 4;
#pragma unroll
    for (int nj = 0; nj < 4; nj++) {
      const int col = n0 + wn * 64 + nj * 16 + l15;
      if (col < NREAL) {
#pragma unroll
        for (int r = 0; r < 4; r++) {
          float v = acc[mi][nj][r];
          if (EPI == 0) {
            if (col < 2 * HD) v = fmaxf(v, 0.f);
            outb[(size_t)(row + r) * NREAL + col] = f2b(v);
          } else {
            outf[(size_t)(row + r) * NREAL + col] = v + bias[col];
          }
        }
      }
    }
  }
#undef STAGE
#undef RD
#undef LGKM0
}

// ===================== 128x128 GEMM (R3, proven; used for GEMM2) ===============
// C[m][n] = sum_k A[m][k] * BT[n][k].  128x128 tile, BK=64, 4 waves (2x2).
// LDS row stride 64 elems; physical seg p holds logical k-seg p^(row&7); staging
// picks the global k-seg per lane so the HW's contiguous lane*16 scatter lands
// swizzled. XCD swizzle: flat%8 = xcd owns m-bands.
template <int EPI, int NC>
__global__ __launch_bounds__(256, 4)
void gemm_bf16_kernel(const uint16_t* __restrict__ A, const uint16_t* __restrict__ BT,
                      uint16_t* __restrict__ outb, float* __restrict__ outf,
                      const float* __restrict__ bias, int K) {
  constexpr int NT = NC / 128;
  __shared__ uint16_t As[128 * 64];
  __shared__ uint16_t Bs[128 * 64];
  const int flat = blockIdx.y * NT + blockIdx.x;
  const int xcd = flat & 7;
  const int s = flat >> 3;
  const int n0 = (s % NT) * 128;
  const int m0 = ((s / NT) * 8 + xcd) * 128;
  const int t = threadIdx.x;
  const int lane = t & 63, w = t >> 6;
  const int wr = w >> 1, wc = w & 1;
  const int l15 = lane & 15, q4 = lane >> 4;
  f32x4 acc[4][4] = {};

  const int srow = w * 32 + (lane >> 3);
  const int sseg = ((lane & 7) ^ (lane >> 3)) * 8;
  const uint16_t* Ag = A + (size_t)(m0 + srow) * K + sseg;
  const uint16_t* Bg = BT + (size_t)(n0 + srow) * K + sseg;
  uint16_t* lA = &As[(w * 32) * 64];
  uint16_t* lB = &Bs[(w * 32) * 64];

  for (int k0 = 0; k0 < K; k0 += 64) {
    __syncthreads();
#pragma unroll
    for (int i = 0; i < 4; i++) {
      GLOAD16(Ag + k0 + (size_t)(i * 8) * K, lA + i * 8 * 64);
      GLOAD16(Bg + k0 + (size_t)(i * 8) * K, lB + i * 8 * 64);
    }
    __syncthreads();
#pragma unroll
    for (int kk = 0; kk < 2; kk++) {
      bf16x8 af[4], bfr[4];
      const int sbase = (kk * 4 + q4);
#pragma unroll
      for (int i = 0; i < 4; i++) {
        const int row = wr * 64 + i * 16 + l15;
        af[i] = *(const bf16x8*)&As[row * 64 + (sbase ^ (l15 & 7)) * 8];
      }
#pragma unroll
      for (int j = 0; j < 4; j++) {
        const int row = wc * 64 + j * 16 + l15;
        bfr[j] = *(const bf16x8*)&Bs[row * 64 + (sbase ^ (l15 & 7)) * 8];
      }
#pragma unroll
      for (int i = 0; i < 4; i++)
#pragma unroll
        for (int j = 0; j < 4; j++)
          acc[i][j] = __builtin_amdgcn_mfma_f32_16x16x32_bf16(af[i], bfr[j], acc[i][j], 0, 0, 0);
    }
  }
#pragma unroll
  for (int i = 0; i < 4; i++) {
#pragma unroll
    for (int j = 0; j < 4; j++) {
      int col = n0 + wc * 64 + j * 16 + l15;
#pragma unroll
      for (int r = 0; r < 4; r++) {
        int row = m0 + wr * 64 + i * 16 + q4 * 4 + r;
        float v = acc[i][j][r];
        if (EPI == 0) {
          if (col < 2 * HD) v = fmaxf(v, 0.f);
          outb[(size_t)row * NC + col] = f2b(v);
        } else {
          outf[(size_t)row * NC + col] = v + bias[col];
        }
      }
    }
  }
}

// kv[d][e] = sum_n k[n,d]*v[n,e] per (b,h); stored transposed kvT[bh][e*32+d]. Also ksum[bh][d].
__global__ __launch_bounds__(64)
void kv_kernel(const uint16_t* __restrict__ qkvb, float* __restrict__ kvT, float* __restrict__ ksum) {
  __shared__ float kb[32][40];
  __shared__ float vb[32][40];
  const int bh = blockIdx.x / KVSPLIT;
  const int sp = blockIdx.x % KVSPLIT;
  const int b = bh / HH, h = bh % HH;
  const int t = threadIdx.x;
  const int d0 = (t >> 3) * 4, e0 = (t & 7) * 4;
  const int m0 = b * NN + sp * (NN / KVSPLIT);
  const size_t koff = (size_t)HD + h * DD;
  const size_t voff = (size_t)2 * HD + h * DD;
  float acc[4][4] = {};
  float ks[4] = {};
  const int srow = t >> 1, sseg = (t & 1) * 16;
  for (int c = 0; c < NN / KVSPLIT; c += 32) {
    const uint16_t* kp = qkvb + (size_t)(m0 + c + srow) * N1 + koff + sseg;
    const uint16_t* vp = qkvb + (size_t)(m0 + c + srow) * N1 + voff + sseg;
    uint4 kr0 = *(const uint4*)kp;
    uint4 kr1 = *(const uint4*)(kp + 8);
    uint4 vr0 = *(const uint4*)vp;
    uint4 vr1 = *(const uint4*)(vp + 8);
    f32x4 klo, khi, klo2, khi2, vlo, vhi, vlo2, vhi2;
    unpack8v(kr0, klo, khi); unpack8v(kr1, klo2, khi2);
    unpack8v(vr0, vlo, vhi); unpack8v(vr1, vlo2, vhi2);
    __syncthreads();
    *(f32x4*)&kb[srow][sseg + 0] = klo;  *(f32x4*)&kb[srow][sseg + 4] = khi;
    *(f32x4*)&kb[srow][sseg + 8] = klo2; *(f32x4*)&kb[srow][sseg + 12] = khi2;
    *(f32x4*)&vb[srow][sseg + 0] = vlo;  *(f32x4*)&vb[srow][sseg + 4] = vhi;
    *(f32x4*)&vb[srow][sseg + 8] = vlo2; *(f32x4*)&vb[srow][sseg + 12] = vhi2;
    __syncthreads();
#pragma unroll 8
    for (int n = 0; n < 32; n++) {
      f32x4 kd = *(const f32x4*)&kb[n][d0];
      f32x4 ve = *(const f32x4*)&vb[n][e0];
#pragma unroll
      for (int i = 0; i < 4; i++)
#pragma unroll
        for (int j = 0; j < 4; j++) acc[i][j] += kd[i] * ve[j];
      if ((t & 7) == 0) {
#pragma unroll
        for (int i = 0; i < 4; i++) ks[i] += kd[i];
      }
    }
  }
#pragma unroll
  for (int i = 0; i < 4; i++)
#pragma unroll
    for (int j = 0; j < 4; j++)
      atomicAdd(&kvT[(size_t)bh * 1024 + (e0 + j) * DD + d0 + i], acc[i][j]);
  if ((t & 7) == 0) {
#pragma unroll
    for (int i = 0; i < 4; i++) atomicAdd(&ksum[bh * DD + d0 + i], ks[i]);
  }
}

// attn[m][h*32+e] = (sum_d q*kv[d][e]) / (sum_d q*ksum[d] + 1e-6), bf16 out.
__global__ __launch_bounds__(256)
void attn_kernel(const uint16_t* __restrict__ qkvb, const float* __restrict__ kvT,
                 const float* __restrict__ ksum, uint16_t* __restrict__ attn) {
  const int t = threadIdx.x;
  const int lane = t & 63, w = t >> 6;
  const int mbase = blockIdx.x * 256 + w * 64;
  const int b = mbase >> 13;
  const int e = lane & 31, dh = lane >> 5;
  const int h0 = blockIdx.y * HPB;
  for (int hh = 0; hh < HPB; hh++) {
    const int h = h0 + hh;
    const int bh = b * HH + h;
    const float* kvp = kvT + (size_t)bh * 1024 + e * DD + dh * 16;
    f32x4 kva = *(const f32x4*)(kvp + 0);
    f32x4 kvb2 = *(const f32x4*)(kvp + 4);
    f32x4 kvc = *(const f32x4*)(kvp + 8);
    f32x4 kvd = *(const f32x4*)(kvp + 12);
    const float* ksp = ksum + bh * DD + dh * 16;
    f32x4 ksa = *(const f32x4*)(ksp + 0);
    f32x4 ksb = *(const f32x4*)(ksp + 4);
    f32x4 ksc = *(const f32x4*)(ksp + 8);
    f32x4 ksd = *(const f32x4*)(ksp + 12);
#pragma unroll 4
    for (int r = 0; r < 64; r++) {
      const int m = mbase + r;
      const uint16_t* qp = qkvb + (size_t)m * N1 + h * DD + dh * 16;
      uint4 q0 = *(const uint4*)qp;
      uint4 q1 = *(const uint4*)(qp + 8);
      f32x4 qa, qb2, qc, qd;
      unpack8v(q0, qa, qb2);
      unpack8v(q1, qc, qd);
      float o = 0.f, den = 0.f;
#pragma unroll
      for (int ii = 0; ii < 4; ii++) {
        o += qa[ii] * kva[ii];  den += qa[ii] * ksa[ii];
        o += qb2[ii] * kvb2[ii]; den += qb2[ii] * ksb[ii];
        o += qc[ii] * kvc[ii];  den += qc[ii] * ksc[ii];
        o += qd[ii] * kvd[ii];  den += qd[ii] * ksd[ii];
      }
      o += __shfl_xor(o, 32);
      den += __shfl_xor(den, 32);
      float res = o / (den + 1e-6f);
      if (dh == 0) attn[(size_t)m * HD + h * DD + e] = f2b(res);
    }
  }
}

extern "C" void kernel_launch(void* const* d_in, const int* in_sizes, int n_in,
                              void* d_out, int out_size, void* d_ws, size_t ws_size,
                              hipStream_t stream) {
  const float* x = (const float*)d_in[0];
  const float* Wqkv = (const float*)d_in[1];
  const float* Wout = (const float*)d_in[2];
  const float* bout = (const float*)d_in[3];
  float* y = (float*)d_out;
  char* ws = (char*)d_ws;
  // workspace layout (bytes):
  //   xb/attn   @ 0          75,497,472  (32768x1152 bf16)
  //   wqkvT     @ 75497472    8,257,536  (3584x1152 bf16, rows>=3456 garbage pad)
  //   qkvb      @ 83755008  226,492,416  (32768x3456 bf16)
  //   kvT       @ 310247424     589,824
  //   ksum      @ 310837248      18,432   total 310,855,680
  //   woutT aliases qkvb (1152x1152 bf16; qkvb dead after attn)
  uint16_t* xb = (uint16_t*)ws;
  uint16_t* wqkvT = (uint16_t*)(ws + 75497472);
  uint16_t* qkvb = (uint16_t*)(ws + 83755008);
  float* kvT = (float*)(ws + 310247424);
  float* ksum = (float*)(ws + 310837248);
  uint16_t* woutT = qkvb;
  uint16_t* attn = xb;  // alias: xb dead after GEMM1

  zero_kernel<<<(152064 + 255) / 256, 256, 0, stream>>>(kvT, 152064);  // kvT+ksum contiguous
  convert_kernel<<<(M_TOT * CC / 4) / 256, 256, 0, stream>>>(x, xb, M_TOT * CC / 4);
  transpose_convert_kernel<<<dim3(N1 / 32, CC / 32), 256, 0, stream>>>(Wqkv, wqkvT, CC, N1);
  gemm256_kernel<0, N1><<<dim3(14, 128), 512, 0, stream>>>(xb, wqkvT, qkvb, nullptr, nullptr);
  kv_kernel<<<144 * KVSPLIT, 64, 0, stream>>>(qkvb, kvT, ksum);
  attn_kernel<<<dim3(M_TOT / 256, HH / HPB), 256, 0, stream>>>(qkvb, kvT, ksum, attn);
  transpose_convert_kernel<<<dim3(CC / 32, CC / 32), 256, 0, stream>>>(Wout, woutT, CC, CC);
  gemm_bf16_kernel<1, CC><<<dim3(CC / 128, M_TOT / 128), 256, 0, stream>>>(attn, woutT, nullptr, y, bout, CC);
}